// Round 2
// baseline (288.446 us; speedup 1.0000x reference)
//
#include <hip/hip_runtime.h>

// Memory-bound masker. Floor: 204.8MB feat + 12.8MB base read + 12.8MB out
// write ~= 230MB => ~37us at 6.3 TB/s.
//
// R1 lesson: per-thread float4[4] loads gave each lane a 64B-strided stream
// (64 distinct lines per load instr) => ~0.8 TB/s. Fix: stage the 256-edge
// x 64B feature tile through LDS with fully-coalesced flat float4 loads,
// stride-17-float padded rows for conflict-free per-edge LDS reads.

#define TILE 256

__global__ __launch_bounds__(256) void ConditionalEdgeMasker_kernel(
    const float* __restrict__ feat,   // (B, E, 16)
    const float* __restrict__ phys,   // (B, 18)
    const float* __restrict__ base,   // (B, E)
    float* __restrict__ out,          // (B, E)
    int E)
{
    __shared__ float s[TILE * 17];    // 17KB: padded rows, 16 used + 1 pad

    const int b  = blockIdx.y;
    const int e0 = blockIdx.x * TILE;
    const int t  = threadIdx.x;

    const int n_edges = min(TILE, E - e0);
    const size_t tile_base = ((size_t)b * E + e0) * 16;  // float index

    // Cooperative coalesced load: TILE*4 float4 chunks, contiguous across
    // the block (lane i reads 16B at +16i => 1KB/wave per instruction).
    #pragma unroll
    for (int k = 0; k < 4; ++k) {
        const int i = t + k * TILE;   // chunk index within tile
        const int e = i >> 2;         // edge within tile (4 chunks/edge)
        if (e < n_edges) {
            const float4 v = *(const float4*)(feat + tile_base + (size_t)i * 4);
            const int p = i & 3;
            float* dst = &s[e * 17 + p * 4];
            dst[0] = v.x; dst[1] = v.y; dst[2] = v.z; dst[3] = v.w;
        }
    }

    // Per-batch physics scalars (uniform address -> scalar loads, L1-cached).
    const float* pp = phys + (size_t)b * 18;
    const float vel  = pp[2];
    const float wall = pp[5];
    const float ke   = pp[9];
    const float cj   = pp[16];
    const float cwj  = pp[17];
    const bool cj_low   = cj < 0.5f;
    const bool wall_low = wall < 0.5f;
    const bool d2 = wall_low || (vel < 0.1f);
    // precedence in ref: wall_low | ((cwj<0.5) & (vel<1.0))
    const bool d4 = wall_low || ((cwj < 0.5f) && (vel < 1.0f));

    __syncthreads();

    if (t >= n_edges) return;

    // Stride-17 rows: bank = (17*t + c) % 32 cycles all 32 banks across the
    // wave -> only the free 2-way (64 lanes / 32 banks) aliasing remains.
    const float* row = &s[t * 17];
    const float f0 = row[0], f1 = row[1], f2 = row[2];
    const float f3 = row[3], f4v = row[4], f5 = row[5];
    const float energy_cost = row[10];
    const float min_v = row[12], max_v = row[13];
    const float req_j = row[14], req_wc = row[15];

    // argmax over cols 0..5, first max -> strict '>'
    int et = 0; float m = f0;
    if (f1  > m) { m = f1;  et = 1; }
    if (f2  > m) { m = f2;  et = 2; }
    if (f3  > m) { m = f3;  et = 3; }
    if (f4v > m) { m = f4v; et = 4; }
    if (f5  > m) { m = f5;  et = 5; }

    // jnp.select: ordered condition chain, default false.
    bool disable;
    if (et == 1 && cj_low)  disable = true;                       // c1
    else if (et == 3)       disable = d2;                         // c2
    else if (req_j > 0.5f)  disable = cj_low || (vel < min_v);    // c3
    else if (req_wc > 0.5f) disable = d4;                         // c4
    else if (et == 1)       disable = (ke < energy_cost * 0.5f);  // c5
    else                    disable = false;

    const bool over  = (max_v > 0.0f) && (vel > max_v);
    const bool under = (!over) && (vel < min_v);
    disable = disable || over || under;

    const size_t idx = (size_t)b * E + e0 + t;
    out[idx] = disable ? 0.0f : base[idx];
}

extern "C" void kernel_launch(void* const* d_in, const int* in_sizes, int n_in,
                              void* d_out, int out_size, void* d_ws, size_t ws_size,
                              hipStream_t stream) {
    const float* feat = (const float*)d_in[0];
    const float* phys = (const float*)d_in[1];
    const float* base = (const float*)d_in[2];
    float* out = (float*)d_out;

    const int B = in_sizes[1] / 18;   // ninja_physics_state is (B, 18)
    const int E = in_sizes[2] / B;    // base_edge_mask is (B, E)

    dim3 block(TILE);
    dim3 grid((E + TILE - 1) / TILE, B);
    ConditionalEdgeMasker_kernel<<<grid, block, 0, stream>>>(feat, phys, base, out, E);
}

// Round 4
// 272.077 us; speedup vs baseline: 1.0602x; 1.0602x over previous
//
#include <hip/hip_runtime.h>

// Memory-bound masker. Mandatory HBM traffic: 204.8MB feat + 12.8MB base +
// 12.8MB out = 230.4MB => ~38us floor at 6.3 TB/s achievable.
//
// R1 vs R2 evidence: strided-direct and LDS-coalesced versions time
// identically (287 vs 288 us total), and the kernel dispatch is <119us
// (absent from rocprof top-5, which is all 120us/800MB harness poison
// fills). dur_us is dominated by fixed harness reset work; the kernel is
// HBM-bound. This round: nontemporal streaming loads/stores (read-once /
// write-once data, skip L2 pollution) + base prefetch before the barrier.
// R3 fix: __builtin_nontemporal_load needs a clang ext_vector_type, not
// HIP_vector_type (float4).

#define TILE 256

typedef float vfloat4 __attribute__((ext_vector_type(4)));

__global__ __launch_bounds__(256) void ConditionalEdgeMasker_kernel(
    const float* __restrict__ feat,   // (B, E, 16)
    const float* __restrict__ phys,   // (B, 18)
    const float* __restrict__ base,   // (B, E)
    float* __restrict__ out,          // (B, E)
    int E)
{
    __shared__ float s[TILE * 17];    // stride-17 rows: conflict-free reads

    const int b  = blockIdx.y;
    const int e0 = blockIdx.x * TILE;
    const int t  = threadIdx.x;

    const int n_edges = min(TILE, E - e0);
    const size_t tile_base = ((size_t)b * E + e0) * 16;  // float index

    // Prefetch this thread's base value (overlaps with LDS staging).
    const size_t idx = (size_t)b * E + e0 + t;
    float base_v = 0.0f;
    if (t < n_edges) base_v = __builtin_nontemporal_load(base + idx);

    // Cooperative coalesced staging: contiguous 16B chunks across the
    // block (1KB/wave per instruction), nontemporal (read-once stream).
    #pragma unroll
    for (int k = 0; k < 4; ++k) {
        const int i = t + k * TILE;   // chunk index within tile
        const int e = i >> 2;         // edge within tile (4 chunks/edge)
        if (e < n_edges) {
            const vfloat4* src = (const vfloat4*)(feat + tile_base + (size_t)i * 4);
            const vfloat4 v = __builtin_nontemporal_load(src);
            const int p = i & 3;
            float* dst = &s[e * 17 + p * 4];
            dst[0] = v.x; dst[1] = v.y; dst[2] = v.z; dst[3] = v.w;
        }
    }

    // Per-batch physics scalars (uniform address -> scalar loads).
    const float* pp = phys + (size_t)b * 18;
    const float vel  = pp[2];
    const float wall = pp[5];
    const float ke   = pp[9];
    const float cj   = pp[16];
    const float cwj  = pp[17];
    const bool cj_low   = cj < 0.5f;
    const bool wall_low = wall < 0.5f;
    const bool d2 = wall_low || (vel < 0.1f);
    // ref precedence: wall_low | ((cwj<0.5) & (vel<1.0))
    const bool d4 = wall_low || ((cwj < 0.5f) && (vel < 1.0f));

    __syncthreads();

    if (t >= n_edges) return;

    const float* row = &s[t * 17];
    const float f0 = row[0], f1 = row[1], f2 = row[2];
    const float f3 = row[3], f4v = row[4], f5 = row[5];
    const float energy_cost = row[10];
    const float min_v = row[12], max_v = row[13];
    const float req_j = row[14], req_wc = row[15];

    // argmax over cols 0..5, first max -> strict '>'
    int et = 0; float m = f0;
    if (f1  > m) { m = f1;  et = 1; }
    if (f2  > m) { m = f2;  et = 2; }
    if (f3  > m) { m = f3;  et = 3; }
    if (f4v > m) { m = f4v; et = 4; }
    if (f5  > m) { m = f5;  et = 5; }

    // jnp.select: ordered condition chain, default false.
    bool disable;
    if (et == 1 && cj_low)  disable = true;                       // c1
    else if (et == 3)       disable = d2;                         // c2
    else if (req_j > 0.5f)  disable = cj_low || (vel < min_v);    // c3
    else if (req_wc > 0.5f) disable = d4;                         // c4
    else if (et == 1)       disable = (ke < energy_cost * 0.5f);  // c5
    else                    disable = false;

    const bool over  = (max_v > 0.0f) && (vel > max_v);
    const bool under = (!over) && (vel < min_v);
    disable = disable || over || under;

    __builtin_nontemporal_store(disable ? 0.0f : base_v, out + idx);
}

extern "C" void kernel_launch(void* const* d_in, const int* in_sizes, int n_in,
                              void* d_out, int out_size, void* d_ws, size_t ws_size,
                              hipStream_t stream) {
    const float* feat = (const float*)d_in[0];
    const float* phys = (const float*)d_in[1];
    const float* base = (const float*)d_in[2];
    float* out = (float*)d_out;

    const int B = in_sizes[1] / 18;   // ninja_physics_state is (B, 18)
    const int E = in_sizes[2] / B;    // base_edge_mask is (B, E)

    dim3 block(TILE);
    dim3 grid((E + TILE - 1) / TILE, B);
    ConditionalEdgeMasker_kernel<<<grid, block, 0, stream>>>(feat, phys, base, out, E);
}